// Round 2
// baseline (450.199 us; speedup 1.0000x reference)
//
#include <hip/hip_runtime.h>
#include <hip/hip_bf16.h>

typedef unsigned short u16;
typedef short short8 __attribute__((ext_vector_type(8)));
typedef float floatx4 __attribute__((ext_vector_type(4)));

#define BB 32
#define TT 64
#define VV 30000
#define EE 64
#define HH 64
#define OO 7
#define KSPLIT 32
#define NU32 937        /* full 32-wide k units: 937*32 = 29984, tail 16 */
#define KTAIL0 29984

__device__ __forceinline__ u16 f2b(float f) {   // fp32 -> bf16, round-to-nearest-even
    unsigned u = __float_as_uint(f);
    u += 0x7FFFu + ((u >> 16) & 1u);
    return (u16)(u >> 16);
}

__device__ __forceinline__ float sigmoid_f(float x) {
    return 1.f / (1.f + __expf(-x));
}

__device__ __forceinline__ float tanh_f(float x) {
    float a = fabsf(x);
    float e = __expf(-2.f * a);
    float t = (1.f - e) / (1.f + e);
    return x < 0.f ? -t : t;
}

// ---------------- Kernel T: transpose + downcast vocab_embed (V x E fp32) -> VT (E x V bf16) ----
__global__ __launch_bounds__(256) void kT(const float* __restrict__ VE, u16* __restrict__ VT) {
    __shared__ u16 tile[64][72];   // +8 pad breaks bank aliasing on column reads
    int v0 = blockIdx.x * 64;
    int t = threadIdx.x;
    #pragma unroll
    for (int i = 0; i < 4; ++i) {
        int c = i * 256 + t;                 // 1024 float4 chunks: 64 rows x 16 chunks
        int row = c >> 4, col4 = (c & 15) * 4;
        if (v0 + row < VV) {
            float4 d = *(const float4*)(VE + (size_t)(v0 + row) * EE + col4);
            ushort4 s;
            s.x = f2b(d.x); s.y = f2b(d.y); s.z = f2b(d.z); s.w = f2b(d.w);
            *(ushort4*)&tile[row][col4] = s;
        }
    }
    __syncthreads();
    int e0 = (t >> 6) * 16;
    int v = t & 63;
    if (v0 + v < VV) {
        #pragma unroll
        for (int ee = 0; ee < 16; ++ee) {
            int e = e0 + ee;
            VT[(size_t)e * VV + v0 + v] = tile[v][e];
        }
    }
}

// ---------------- Kernel E: embed GEMM (split-K, no LDS, no barriers) + fused row-sum ----------
// Cpart[kb][m][e] = sum_{k in slice} x[m][k]*VE[k][e];  Rpart[kb][m] = sum_{k in slice} x[m][k]
__global__ __launch_bounds__(256) void kE(const float* __restrict__ x, const u16* __restrict__ vt,
                                          float* __restrict__ Cpart, float* __restrict__ Rpart) {
    int tid = threadIdx.x;
    int w = tid >> 6, l = tid & 63;
    int r15 = l & 15, q = l >> 4;
    int mb = blockIdx.x, kb = blockIdx.y;
    int m0 = mb * 64;
    int wr = m0 + w * 16;                    // this wave's 16 m-rows

    const float* aRow = x + (size_t)(wr + r15) * VV;       // A[m=l&15][k]
    const u16* b0p = vt + (size_t)(r15)      * VV;         // B[k][n=l&15], n-block 0..3
    const u16* b1p = vt + (size_t)(16 + r15) * VV;
    const u16* b2p = vt + (size_t)(32 + r15) * VV;
    const u16* b3p = vt + (size_t)(48 + r15) * VV;

    floatx4 acc[4] = {};
    floatx4 accS = {};
    short8 ones;
    #pragma unroll
    for (int i = 0; i < 8; ++i) ones[i] = (short)0x3F80;   // bf16 1.0

    int u0 = (kb * NU32) / KSPLIT, u1 = ((kb + 1) * NU32) / KSPLIT;

    #pragma unroll 2
    for (int u = u0; u < u1; ++u) {
        int k0 = u * 32 + q * 8;             // lane's 8-k slice
        float4 a0 = *(const float4*)(aRow + k0);
        float4 a1 = *(const float4*)(aRow + k0 + 4);
        short8 bf0 = *(const short8*)(b0p + k0);
        short8 bf1 = *(const short8*)(b1p + k0);
        short8 bf2 = *(const short8*)(b2p + k0);
        short8 bf3 = *(const short8*)(b3p + k0);
        short8 af;
        af[0] = (short)f2b(a0.x); af[1] = (short)f2b(a0.y);
        af[2] = (short)f2b(a0.z); af[3] = (short)f2b(a0.w);
        af[4] = (short)f2b(a1.x); af[5] = (short)f2b(a1.y);
        af[6] = (short)f2b(a1.z); af[7] = (short)f2b(a1.w);
        acc[0] = __builtin_amdgcn_mfma_f32_16x16x32_bf16(af, bf0, acc[0], 0, 0, 0);
        acc[1] = __builtin_amdgcn_mfma_f32_16x16x32_bf16(af, bf1, acc[1], 0, 0, 0);
        acc[2] = __builtin_amdgcn_mfma_f32_16x16x32_bf16(af, bf2, acc[2], 0, 0, 0);
        acc[3] = __builtin_amdgcn_mfma_f32_16x16x32_bf16(af, bf3, acc[3], 0, 0, 0);
        accS   = __builtin_amdgcn_mfma_f32_16x16x32_bf16(af, ones, accS, 0, 0, 0);
    }

    if (kb == KSPLIT - 1) {
        // K-tail: 16 real k, zero-pad the upper 16 of the 32-wide MFMA
        short8 af, bf0, bf1, bf2, bf3;
        #pragma unroll
        for (int i = 0; i < 8; ++i) { af[i] = 0; bf0[i] = 0; bf1[i] = 0; bf2[i] = 0; bf3[i] = 0; }
        if (q < 2) {
            int k0 = KTAIL0 + q * 8;
            float4 a0 = *(const float4*)(aRow + k0);
            float4 a1 = *(const float4*)(aRow + k0 + 4);
            af[0] = (short)f2b(a0.x); af[1] = (short)f2b(a0.y);
            af[2] = (short)f2b(a0.z); af[3] = (short)f2b(a0.w);
            af[4] = (short)f2b(a1.x); af[5] = (short)f2b(a1.y);
            af[6] = (short)f2b(a1.z); af[7] = (short)f2b(a1.w);
            bf0 = *(const short8*)(b0p + k0);
            bf1 = *(const short8*)(b1p + k0);
            bf2 = *(const short8*)(b2p + k0);
            bf3 = *(const short8*)(b3p + k0);
        }
        acc[0] = __builtin_amdgcn_mfma_f32_16x16x32_bf16(af, bf0, acc[0], 0, 0, 0);
        acc[1] = __builtin_amdgcn_mfma_f32_16x16x32_bf16(af, bf1, acc[1], 0, 0, 0);
        acc[2] = __builtin_amdgcn_mfma_f32_16x16x32_bf16(af, bf2, acc[2], 0, 0, 0);
        acc[3] = __builtin_amdgcn_mfma_f32_16x16x32_bf16(af, bf3, acc[3], 0, 0, 0);
        accS   = __builtin_amdgcn_mfma_f32_16x16x32_bf16(af, ones, accS, 0, 0, 0);
    }

    // epilogue: C/D layout is col = lane&15, row = (lane>>4)*4 + reg
    float* Cp = Cpart + (size_t)kb * (2048 * 64);
    #pragma unroll
    for (int r = 0; r < 4; ++r) {
        int row = wr + q * 4 + r;
        #pragma unroll
        for (int n = 0; n < 4; ++n)
            Cp[(size_t)row * 64 + n * 16 + r15] = acc[n][r];
        if (r15 == 0) Rpart[kb * 2048 + row] = accS[r];
    }
}

// ---------------- Kernel G: finish embed (relu(c/rs)) + input-gate precompute + h0 --------------
__global__ __launch_bounds__(64) void kG(const float* __restrict__ Cpart, const float* __restrict__ Rpart,
                                         const float* __restrict__ Wir, const float* __restrict__ Wiz,
                                         const float* __restrict__ Win,
                                         const float* __restrict__ bir, const float* __restrict__ biz,
                                         const float* __restrict__ bin,
                                         float* __restrict__ Xr, float* __restrict__ Xz,
                                         float* __restrict__ Xn, float* __restrict__ H0) {
    int m = blockIdx.x;
    int j = threadIdx.x;
    __shared__ float e[64];
    float c = 0.f, rs = 0.f;
    #pragma unroll
    for (int kb = 0; kb < KSPLIT; ++kb) {
        c  += Cpart[(size_t)kb * 2048 * 64 + m * 64 + j];
        rs += Rpart[kb * 2048 + m];
    }
    float ev = c / rs;
    e[j] = ev > 0.f ? ev : 0.f;
    __syncthreads();
    float ar = bir[j], az = biz[j], an = bin[j];
    #pragma unroll 4
    for (int i = 0; i < 64; ++i) {
        float ei = e[i];
        ar += ei * Wir[j * 64 + i];
        az += ei * Wiz[j * 64 + i];
        an += ei * Win[j * 64 + i];
    }
    Xr[m * 64 + j] = ar;
    Xz[m * 64 + j] = az;
    Xn[m * 64 + j] = an;
    if ((m & 63) == 0) {       // t == 0: initial hidden state
        int b = m >> 6;
        float z1 = sigmoid_f(az);
        float n1 = tanh_f(an);
        H0[b * 64 + j] = (1.f - z1) * n1;
    }
}

// ---------------- Kernel S: sequential GRU scan (one block per batch) + output proj -------------
__global__ __launch_bounds__(256) void kS(const float* __restrict__ Xr, const float* __restrict__ Xz,
                                          const float* __restrict__ Xn, const float* __restrict__ H0,
                                          const float* __restrict__ Whr, const float* __restrict__ Whz,
                                          const float* __restrict__ bhr, const float* __restrict__ bhz,
                                          const float* __restrict__ Wout, const float* __restrict__ bout,
                                          float* __restrict__ out) {
    int b = blockIdx.x;
    int tid = threadIdx.x;
    int i = tid & 63, jw = tid >> 6;
    __shared__ float XsR[64 * 64], XsZ[64 * 64], XsN[64 * 64];
    __shared__ float h[64];
    __shared__ float P[4][2][64];

    const float* xr = Xr + (size_t)b * 4096;
    const float* xz = Xz + (size_t)b * 4096;
    const float* xn = Xn + (size_t)b * 4096;
    #pragma unroll
    for (int it = 0; it < 4; ++it) {
        int off = it * 1024 + tid * 4;
        *(float4*)&XsR[off] = *(const float4*)&xr[off];
        *(float4*)&XsZ[off] = *(const float4*)&xz[off];
        *(float4*)&XsN[off] = *(const float4*)&xn[off];
    }
    // per-thread slice of W_hr/W_hz rows (j = jw*16 .. jw*16+15), held in registers
    float wr[16], wz[16];
    #pragma unroll
    for (int jj = 0; jj < 16; ++jj) {
        wr[jj] = Whr[i * 64 + jw * 16 + jj];
        wz[jj] = Whz[i * 64 + jw * 16 + jj];
    }
    float bhr_i = bhr[i];
    float bhz_i = bhz[i];
    if (tid < 64) h[tid] = H0[b * 64 + tid];
    __syncthreads();

    for (int t = 1; t < 64; ++t) {
        float pr = 0.f, pz = 0.f;
        #pragma unroll
        for (int jj = 0; jj < 16; ++jj) {
            float hj = h[jw * 16 + jj];   // wave-uniform LDS broadcast
            pr += hj * wr[jj];
            pz += hj * wz[jj];
        }
        P[jw][0][i] = pr;
        P[jw][1][i] = pz;
        __syncthreads();
        if (tid < 64) {
            float hr = bhr_i + P[0][0][i] + P[1][0][i] + P[2][0][i] + P[3][0][i];
            float hz = bhz_i + P[0][1][i] + P[1][1][i] + P[2][1][i] + P[3][1][i];
            float r = sigmoid_f(XsR[t * 64 + i] + hr);
            float z = sigmoid_f(XsZ[t * 64 + i] + hz);
            float n = tanh_f(XsN[t * 64 + i] + r * hr);   // ref uses r*hr: W_hn/b_hn are dead
            h[i] = (1.f - z) * n + z * h[i];
        }
        __syncthreads();
    }

    if (tid < OO) {
        float acc2 = bout[tid];
        #pragma unroll 8
        for (int ii = 0; ii < 64; ++ii)
            acc2 += h[ii] * Wout[tid * 64 + ii];
        out[b * OO + tid] = acc2;
    }
}

extern "C" void kernel_launch(void* const* d_in, const int* in_sizes, int n_in,
                              void* d_out, int out_size, void* d_ws, size_t ws_size,
                              hipStream_t stream) {
    const float* x    = (const float*)d_in[0];
    const float* VE   = (const float*)d_in[1];
    const float* Wir  = (const float*)d_in[2];
    const float* Wiz  = (const float*)d_in[3];
    const float* Win  = (const float*)d_in[4];
    const float* Whr  = (const float*)d_in[5];
    const float* Whz  = (const float*)d_in[6];
    // d_in[7] = W_hn (dead in the reference recurrence)
    const float* bir  = (const float*)d_in[8];
    const float* biz  = (const float*)d_in[9];
    const float* bin  = (const float*)d_in[10];
    const float* bhr  = (const float*)d_in[11];
    const float* bhz  = (const float*)d_in[12];
    // d_in[13] = b_hn (dead)
    const float* Wout = (const float*)d_in[14];
    const float* bout = (const float*)d_in[15];

    char* ws = (char*)d_ws;
    u16*   VT    = (u16*)(ws);                              //  3,840,000 B
    float* Cpart = (float*)(ws + 3840000);                  // 16,777,216 B
    float* Rpart = (float*)(ws + 3840000 + 16777216);       //    262,144 B
    float* Xr    = (float*)(ws + 20879360);                 //    524,288 B
    float* Xz    = (float*)(ws + 21403648);                 //    524,288 B
    float* Xn    = (float*)(ws + 21927936);                 //    524,288 B
    float* H0    = (float*)(ws + 22452224);                 //      8,192 B

    kT<<<(VV + 63) / 64, 256, 0, stream>>>(VE, VT);
    kE<<<dim3(2048 / 64, KSPLIT), 256, 0, stream>>>(x, VT, Cpart, Rpart);
    kG<<<2048, 64, 0, stream>>>(Cpart, Rpart, Wir, Wiz, Win, bir, biz, bin, Xr, Xz, Xn, H0);
    kS<<<BB, 256, 0, stream>>>(Xr, Xz, Xn, H0, Whr, Whz, bhr, bhz, Wout, bout, (float*)d_out);
}

// Round 3
// 447.375 us; speedup vs baseline: 1.0063x; 1.0063x over previous
//
#include <hip/hip_runtime.h>
#include <hip/hip_bf16.h>

typedef unsigned short u16;
typedef short short8 __attribute__((ext_vector_type(8)));
typedef float floatx4 __attribute__((ext_vector_type(4)));

#define BB 32
#define TT 64
#define VV 30000
#define EE 64
#define HH 64
#define OO 7
#define KSPLIT 32
#define NU32 937        /* full 32-wide k units: 937*32 = 29984, tail 16 */
#define KTAIL0 29984

__device__ __forceinline__ u16 f2b(float f) {   // fp32 -> bf16, round-to-nearest-even
    unsigned u = __float_as_uint(f);
    u += 0x7FFFu + ((u >> 16) & 1u);
    return (u16)(u >> 16);
}

// pack hi16(fe), hi16(fo) -> one VGPR via v_perm_b32 (bf16 truncation)
__device__ __forceinline__ unsigned pk2(float fo, float fe) {
    return __builtin_amdgcn_perm(__float_as_uint(fo), __float_as_uint(fe), 0x07060302u);
}

__device__ __forceinline__ float sigmoid_f(float x) {
    return 1.f / (1.f + __expf(-x));
}

__device__ __forceinline__ float tanh_f(float x) {
    float a = fabsf(x);
    float e = __expf(-2.f * a);
    float t = (1.f - e) / (1.f + e);
    return x < 0.f ? -t : t;
}

// ---------------- Kernel T: transpose + downcast vocab_embed (V x E fp32) -> VT (E x V bf16) ----
__global__ __launch_bounds__(256) void kT(const float* __restrict__ VE, u16* __restrict__ VT) {
    __shared__ u16 tile[64][72];
    int v0 = blockIdx.x * 64;
    int t = threadIdx.x;
    #pragma unroll
    for (int i = 0; i < 4; ++i) {
        int c = i * 256 + t;                 // 1024 float4 chunks: 64 rows x 16 chunks
        int row = c >> 4, col4 = (c & 15) * 4;
        if (v0 + row < VV) {
            float4 d = *(const float4*)(VE + (size_t)(v0 + row) * EE + col4);
            ushort4 s;
            s.x = f2b(d.x); s.y = f2b(d.y); s.z = f2b(d.z); s.w = f2b(d.w);
            *(ushort4*)&tile[row][col4] = s;
        }
    }
    __syncthreads();
    int e0 = (t >> 6) * 16;
    int v = t & 63;
    if (v0 + v < VV) {
        #pragma unroll
        for (int ee = 0; ee < 16; ++ee) {
            int e = e0 + ee;
            VT[(size_t)e * VV + v0 + v] = tile[v][e];
        }
    }
}

// ---------------- Kernel E: embed GEMM (split-K, no LDS, no barriers) + fused row-sum ----------
__global__ __launch_bounds__(256) void kE(const float* __restrict__ x, const u16* __restrict__ vt,
                                          float* __restrict__ Cpart, float* __restrict__ Rpart) {
    int tid = threadIdx.x;
    int w = tid >> 6, l = tid & 63;
    int r15 = l & 15, q = l >> 4;
    int mb = blockIdx.x, kb = blockIdx.y;
    int m0 = mb * 64;
    int wr = m0 + w * 16;                    // this wave's 16 m-rows

    const float* aRow = x + (size_t)(wr + r15) * VV;       // A[m=l&15][k]
    const u16* b0p = vt + (size_t)(r15)      * VV;         // B[k][n=l&15], n-block 0..3
    const u16* b1p = vt + (size_t)(16 + r15) * VV;
    const u16* b2p = vt + (size_t)(32 + r15) * VV;
    const u16* b3p = vt + (size_t)(48 + r15) * VV;

    floatx4 acc[4] = {};
    floatx4 accS = {};
    short8 ones;
    #pragma unroll
    for (int i = 0; i < 8; ++i) ones[i] = (short)0x3F80;   // bf16 1.0

    int u0 = (kb * NU32) / KSPLIT, u1 = ((kb + 1) * NU32) / KSPLIT;

    #pragma unroll 2
    for (int u = u0; u < u1; ++u) {
        int k0 = u * 32 + q * 8;             // lane's 8-k slice
        float4 a0 = *(const float4*)(aRow + k0);
        float4 a1 = *(const float4*)(aRow + k0 + 4);
        short8 bf0 = *(const short8*)(b0p + k0);
        short8 bf1 = *(const short8*)(b1p + k0);
        short8 bf2 = *(const short8*)(b2p + k0);
        short8 bf3 = *(const short8*)(b3p + k0);
        short8 af;
        unsigned* afu = (unsigned*)&af;
        afu[0] = pk2(a0.y, a0.x);
        afu[1] = pk2(a0.w, a0.z);
        afu[2] = pk2(a1.y, a1.x);
        afu[3] = pk2(a1.w, a1.z);
        acc[0] = __builtin_amdgcn_mfma_f32_16x16x32_bf16(af, bf0, acc[0], 0, 0, 0);
        acc[1] = __builtin_amdgcn_mfma_f32_16x16x32_bf16(af, bf1, acc[1], 0, 0, 0);
        acc[2] = __builtin_amdgcn_mfma_f32_16x16x32_bf16(af, bf2, acc[2], 0, 0, 0);
        acc[3] = __builtin_amdgcn_mfma_f32_16x16x32_bf16(af, bf3, acc[3], 0, 0, 0);
        accS   = __builtin_amdgcn_mfma_f32_16x16x32_bf16(af, ones, accS, 0, 0, 0);
    }

    if (kb == KSPLIT - 1) {
        // K-tail: 16 real k, zero-pad the upper 16 of the 32-wide MFMA
        short8 af, bf0, bf1, bf2, bf3;
        #pragma unroll
        for (int i = 0; i < 8; ++i) { af[i] = 0; bf0[i] = 0; bf1[i] = 0; bf2[i] = 0; bf3[i] = 0; }
        if (q < 2) {
            int k0 = KTAIL0 + q * 8;
            float4 a0 = *(const float4*)(aRow + k0);
            float4 a1 = *(const float4*)(aRow + k0 + 4);
            unsigned* afu = (unsigned*)&af;
            afu[0] = pk2(a0.y, a0.x);
            afu[1] = pk2(a0.w, a0.z);
            afu[2] = pk2(a1.y, a1.x);
            afu[3] = pk2(a1.w, a1.z);
            bf0 = *(const short8*)(b0p + k0);
            bf1 = *(const short8*)(b1p + k0);
            bf2 = *(const short8*)(b2p + k0);
            bf3 = *(const short8*)(b3p + k0);
        }
        acc[0] = __builtin_amdgcn_mfma_f32_16x16x32_bf16(af, bf0, acc[0], 0, 0, 0);
        acc[1] = __builtin_amdgcn_mfma_f32_16x16x32_bf16(af, bf1, acc[1], 0, 0, 0);
        acc[2] = __builtin_amdgcn_mfma_f32_16x16x32_bf16(af, bf2, acc[2], 0, 0, 0);
        acc[3] = __builtin_amdgcn_mfma_f32_16x16x32_bf16(af, bf3, acc[3], 0, 0, 0);
        accS   = __builtin_amdgcn_mfma_f32_16x16x32_bf16(af, ones, accS, 0, 0, 0);
    }

    // epilogue: C/D layout is col = lane&15, row = (lane>>4)*4 + reg
    float* Cp = Cpart + (size_t)kb * (2048 * 64);
    #pragma unroll
    for (int r = 0; r < 4; ++r) {
        int row = wr + q * 4 + r;
        #pragma unroll
        for (int n = 0; n < 4; ++n)
            Cp[(size_t)row * 64 + n * 16 + r15] = acc[n][r];
        if (r15 == 0) Rpart[kb * 2048 + row] = accS[r];
    }
}

// ---------------- Kernel G2: fused embed-finish + gate GEMM (MFMA) + h0 -------------------------
// grid 32 blocks (one per 64 m-rows), 256 threads
__global__ __launch_bounds__(256) void kG2(const float* __restrict__ Cpart, const float* __restrict__ Rpart,
                                           const float* __restrict__ Wir, const float* __restrict__ Wiz,
                                           const float* __restrict__ Win,
                                           const float* __restrict__ bir, const float* __restrict__ biz,
                                           const float* __restrict__ bin,
                                           float* __restrict__ Xr, float* __restrict__ Xz,
                                           float* __restrict__ Xn, float* __restrict__ H0) {
    __shared__ __align__(16) u16 eL[64 * 72];   // e-tile, bf16, 144B pitch (16B aligned, 2-way banks)
    __shared__ float rsinv[64];
    int tid = threadIdx.x;
    int m0 = blockIdx.x * 64;

    // --- phase 1a: row-sum reduction ---
    if (tid < 64) {
        float rs = 0.f;
        #pragma unroll
        for (int kb = 0; kb < KSPLIT; ++kb)
            rs += Rpart[kb * 2048 + m0 + tid];
        rsinv[tid] = 1.f / rs;
    }
    // --- phase 1b: Cpart reduction, coalesced (16 KB contiguous per kb) ---
    float4 a4[4];
    #pragma unroll
    for (int r = 0; r < 4; ++r) { a4[r].x = 0.f; a4[r].y = 0.f; a4[r].z = 0.f; a4[r].w = 0.f; }
    const float* cp = Cpart + (size_t)m0 * 64 + tid * 4;
    #pragma unroll 4
    for (int kb = 0; kb < KSPLIT; ++kb) {
        #pragma unroll
        for (int r = 0; r < 4; ++r) {
            float4 v = *(const float4*)(cp + (size_t)kb * (2048 * 64) + r * 1024);
            a4[r].x += v.x; a4[r].y += v.y; a4[r].z += v.z; a4[r].w += v.w;
        }
    }
    __syncthreads();                       // rsinv visible
    #pragma unroll
    for (int r = 0; r < 4; ++r) {
        int m = r * 16 + (tid >> 4);       // local row
        float ri = rsinv[m];
        float e0 = a4[r].x * ri, e1 = a4[r].y * ri, e2 = a4[r].z * ri, e3 = a4[r].w * ri;
        e0 = e0 > 0.f ? e0 : 0.f;  e1 = e1 > 0.f ? e1 : 0.f;
        e2 = e2 > 0.f ? e2 : 0.f;  e3 = e3 > 0.f ? e3 : 0.f;
        ushort4 s;
        s.x = f2b(e0); s.y = f2b(e1); s.z = f2b(e2); s.w = f2b(e3);
        *(ushort4*)&eL[m * 72 + (tid & 15) * 4] = s;
    }
    __syncthreads();

    // --- phase 2: three gate GEMMs, 16x16x32 MFMA, K=64 ---
    int w = tid >> 6, l = tid & 63;
    int r15 = l & 15, q = l >> 4;
    short8 a0 = *(const short8*)&eL[(w * 16 + r15) * 72 + q * 8];        // k = 0..31
    short8 a1 = *(const short8*)&eL[(w * 16 + r15) * 72 + 32 + q * 8];   // k = 32..63

    floatx4 acc[3][4] = {};
    const float* Wg0 = Wir; const float* Wg1 = Wiz; const float* Wg2 = Win;
    #pragma unroll
    for (int g = 0; g < 3; ++g) {
        const float* W = (g == 0) ? Wg0 : (g == 1) ? Wg1 : Wg2;
        #pragma unroll
        for (int nb = 0; nb < 4; ++nb) {
            const float* wrow = W + (nb * 16 + r15) * 64 + q * 8;   // B[k][n] = W[n][k]
            float4 w0 = *(const float4*)(wrow);
            float4 w1 = *(const float4*)(wrow + 4);
            float4 w2 = *(const float4*)(wrow + 32);
            float4 w3 = *(const float4*)(wrow + 36);
            short8 b0, b1;
            unsigned* b0u = (unsigned*)&b0; unsigned* b1u = (unsigned*)&b1;
            b0u[0] = pk2(w0.y, w0.x); b0u[1] = pk2(w0.w, w0.z);
            b0u[2] = pk2(w1.y, w1.x); b0u[3] = pk2(w1.w, w1.z);
            b1u[0] = pk2(w2.y, w2.x); b1u[1] = pk2(w2.w, w2.z);
            b1u[2] = pk2(w3.y, w3.x); b1u[3] = pk2(w3.w, w3.z);
            acc[g][nb] = __builtin_amdgcn_mfma_f32_16x16x32_bf16(a0, b0, acc[g][nb], 0, 0, 0);
            acc[g][nb] = __builtin_amdgcn_mfma_f32_16x16x32_bf16(a1, b1, acc[g][nb], 0, 0, 0);
        }
    }

    // --- epilogue: bias + store; C/D layout col=lane&15, row=q*4+reg ---
    #pragma unroll
    for (int g = 0; g < 3; ++g) {
        float* Xo = (g == 0) ? Xr : (g == 1) ? Xz : Xn;
        const float* bo = (g == 0) ? bir : (g == 1) ? biz : bin;
        #pragma unroll
        for (int nb = 0; nb < 4; ++nb) {
            int j = nb * 16 + r15;
            float bias = bo[j];
            #pragma unroll
            for (int r = 0; r < 4; ++r) {
                int m = m0 + w * 16 + q * 4 + r;
                Xo[(size_t)m * 64 + j] = acc[g][nb][r] + bias;
            }
        }
    }
    // h0 from the t=0 row (first row of this block: w==0, q==0, reg 0)
    if (w == 0 && q == 0) {
        #pragma unroll
        for (int nb = 0; nb < 4; ++nb) {
            int j = nb * 16 + r15;
            float z1 = sigmoid_f(acc[1][nb][0] + biz[j]);
            float n1 = tanh_f(acc[2][nb][0] + bin[j]);
            H0[blockIdx.x * 64 + j] = (1.f - z1) * n1;
        }
    }
}

// ---------------- Kernel S: sequential GRU scan (one block per batch) + output proj -------------
__global__ __launch_bounds__(256) void kS(const float* __restrict__ Xr, const float* __restrict__ Xz,
                                          const float* __restrict__ Xn, const float* __restrict__ H0,
                                          const float* __restrict__ Whr, const float* __restrict__ Whz,
                                          const float* __restrict__ bhr, const float* __restrict__ bhz,
                                          const float* __restrict__ Wout, const float* __restrict__ bout,
                                          float* __restrict__ out) {
    int b = blockIdx.x;
    int tid = threadIdx.x;
    int i = tid & 63, jw = tid >> 6;
    __shared__ float XsR[64 * 64], XsZ[64 * 64], XsN[64 * 64];
    __shared__ float h[64];
    __shared__ float P[4][2][64];

    const float* xr = Xr + (size_t)b * 4096;
    const float* xz = Xz + (size_t)b * 4096;
    const float* xn = Xn + (size_t)b * 4096;
    #pragma unroll
    for (int it = 0; it < 4; ++it) {
        int off = it * 1024 + tid * 4;
        *(float4*)&XsR[off] = *(const float4*)&xr[off];
        *(float4*)&XsZ[off] = *(const float4*)&xz[off];
        *(float4*)&XsN[off] = *(const float4*)&xn[off];
    }
    float wr[16], wz[16];
    #pragma unroll
    for (int jj = 0; jj < 16; ++jj) {
        wr[jj] = Whr[i * 64 + jw * 16 + jj];
        wz[jj] = Whz[i * 64 + jw * 16 + jj];
    }
    float bhr_i = bhr[i];
    float bhz_i = bhz[i];
    if (tid < 64) h[tid] = H0[b * 64 + tid];
    __syncthreads();

    for (int t = 1; t < 64; ++t) {
        float pr = 0.f, pz = 0.f;
        #pragma unroll
        for (int jj = 0; jj < 16; ++jj) {
            float hj = h[jw * 16 + jj];
            pr += hj * wr[jj];
            pz += hj * wz[jj];
        }
        P[jw][0][i] = pr;
        P[jw][1][i] = pz;
        __syncthreads();
        if (tid < 64) {
            float hr = bhr_i + P[0][0][i] + P[1][0][i] + P[2][0][i] + P[3][0][i];
            float hz = bhz_i + P[0][1][i] + P[1][1][i] + P[2][1][i] + P[3][1][i];
            float r = sigmoid_f(XsR[t * 64 + i] + hr);
            float z = sigmoid_f(XsZ[t * 64 + i] + hz);
            float n = tanh_f(XsN[t * 64 + i] + r * hr);   // ref uses r*hr: W_hn/b_hn are dead
            h[i] = (1.f - z) * n + z * h[i];
        }
        __syncthreads();
    }

    if (tid < OO) {
        float acc2 = bout[tid];
        #pragma unroll 8
        for (int ii = 0; ii < 64; ++ii)
            acc2 += h[ii] * Wout[tid * 64 + ii];
        out[b * OO + tid] = acc2;
    }
}

extern "C" void kernel_launch(void* const* d_in, const int* in_sizes, int n_in,
                              void* d_out, int out_size, void* d_ws, size_t ws_size,
                              hipStream_t stream) {
    const float* x    = (const float*)d_in[0];
    const float* VE   = (const float*)d_in[1];
    const float* Wir  = (const float*)d_in[2];
    const float* Wiz  = (const float*)d_in[3];
    const float* Win  = (const float*)d_in[4];
    const float* Whr  = (const float*)d_in[5];
    const float* Whz  = (const float*)d_in[6];
    // d_in[7] = W_hn (dead in the reference recurrence)
    const float* bir  = (const float*)d_in[8];
    const float* biz  = (const float*)d_in[9];
    const float* bin  = (const float*)d_in[10];
    const float* bhr  = (const float*)d_in[11];
    const float* bhz  = (const float*)d_in[12];
    // d_in[13] = b_hn (dead)
    const float* Wout = (const float*)d_in[14];
    const float* bout = (const float*)d_in[15];

    char* ws = (char*)d_ws;
    u16*   VT    = (u16*)(ws);                              //  3,840,000 B
    float* Cpart = (float*)(ws + 3840000);                  // 16,777,216 B
    float* Rpart = (float*)(ws + 3840000 + 16777216);       //    262,144 B
    float* Xr    = (float*)(ws + 20879360);                 //    524,288 B
    float* Xz    = (float*)(ws + 21403648);                 //    524,288 B
    float* Xn    = (float*)(ws + 21927936);                 //    524,288 B
    float* H0    = (float*)(ws + 22452224);                 //      8,192 B

    kT<<<(VV + 63) / 64, 256, 0, stream>>>(VE, VT);
    kE<<<dim3(2048 / 64, KSPLIT), 256, 0, stream>>>(x, VT, Cpart, Rpart);
    kG2<<<32, 256, 0, stream>>>(Cpart, Rpart, Wir, Wiz, Win, bir, biz, bin, Xr, Xz, Xn, H0);
    kS<<<BB, 256, 0, stream>>>(Xr, Xz, Xn, H0, Whr, Whz, bhr, bhz, Wout, bout, (float*)d_out);
}

// Round 4
// 435.269 us; speedup vs baseline: 1.0343x; 1.0278x over previous
//
#include <hip/hip_runtime.h>
#include <hip/hip_bf16.h>

typedef unsigned short u16;
typedef short short8 __attribute__((ext_vector_type(8)));
typedef float floatx4 __attribute__((ext_vector_type(4)));

#define BB 32
#define TT 64
#define VV 30000
#define EE 64
#define HH 64
#define OO 7
#define KSPLIT 32
#define NU32 937        /* full 32-wide k units: 937*32 = 29984, tail 16 */

__device__ __forceinline__ u16 f2b(float f) {   // fp32 -> bf16, round-to-nearest-even
    unsigned u = __float_as_uint(f);
    u += 0x7FFFu + ((u >> 16) & 1u);
    return (u16)(u >> 16);
}

// pack hi16(fe), hi16(fo) -> one VGPR via v_perm_b32 (bf16 truncation)
__device__ __forceinline__ unsigned pk2(float fo, float fe) {
    return __builtin_amdgcn_perm(__float_as_uint(fo), __float_as_uint(fe), 0x07060302u);
}

__device__ __forceinline__ float sigmoid_f(float x) {
    return 1.f / (1.f + __expf(-x));
}

__device__ __forceinline__ float tanh_f(float x) {
    float a = fabsf(x);
    float e = __expf(-2.f * a);
    float t = (1.f - e) / (1.f + e);
    return x < 0.f ? -t : t;
}

// ---------------- Kernel T: VE (V x E fp32) -> fragment-major bf16 VTf ----
// VTf chunk u (4 KB): [nb 0..3][r15 0..15][k 0..31] = B[k = u*32+k][n = nb*16+r15]
// chunks u = 0..937; u=937 has k>=16 zero-padded (and v>=30000 zero).
__global__ __launch_bounds__(256) void kT(const float* __restrict__ VE, u16* __restrict__ VTf) {
    __shared__ u16 tile[64][72];
    int v0 = blockIdx.x * 64;
    int t = threadIdx.x;
    #pragma unroll
    for (int it = 0; it < 4; ++it) {
        int c = it * 256 + t;                // 1024 float4 chunks: 64 rows x 16 chunks
        int row = c >> 4, col4 = (c & 15) * 4;
        ushort4 s; s.x = 0; s.y = 0; s.z = 0; s.w = 0;
        if (v0 + row < VV) {
            float4 d = *(const float4*)(VE + (size_t)(v0 + row) * EE + col4);
            s.x = f2b(d.x); s.y = f2b(d.y); s.z = f2b(d.z); s.w = f2b(d.w);
        }
        *(ushort4*)&tile[row][col4] = s;
    }
    __syncthreads();
    int e = t & 63;
    int nb = e >> 4, r = e & 15;
    #pragma unroll
    for (int half = 0; half < 2; ++half) {
        int q8 = (t >> 6) + half * 4;        // 0..7 -> v-local = q8*8 .. +7
        int u = (v0 >> 5) + (q8 >> 2);
        int kin = (q8 & 3) * 8;
        u16 tmp[8];
        #pragma unroll
        for (int jj = 0; jj < 8; ++jj) tmp[jj] = tile[q8 * 8 + jj][e];
        *(uint4*)&VTf[(size_t)u * 2048 + nb * 512 + r * 32 + kin] = *(uint4*)tmp;
    }
}

// ---------------- Kernel E: embed GEMM (split-K, no LDS, no barriers) + fused row-sum ----------
__global__ __launch_bounds__(256) void kE(const float* __restrict__ x, const u16* __restrict__ vtf,
                                          float* __restrict__ Cpart, float* __restrict__ Rpart) {
    int tid = threadIdx.x;
    int w = tid >> 6, l = tid & 63;
    int r15 = l & 15, q = l >> 4;
    int mb = blockIdx.x, kb = blockIdx.y;
    int m0 = mb * 64;
    int wr = m0 + w * 16;                    // this wave's 16 m-rows
    int u0 = (kb * NU32) / KSPLIT, u1 = ((kb + 1) * NU32) / KSPLIT;

    const float* aP = x + (size_t)(wr + r15) * VV + u0 * 32 + q * 8;
    const u16*   bP = vtf + (size_t)u0 * 2048 + r15 * 32 + q * 8;

    floatx4 acc[4] = {};
    floatx4 accS = {};
    short8 ones;
    #pragma unroll
    for (int i = 0; i < 8; ++i) ones[i] = (short)0x3F80;   // bf16 1.0

    #pragma unroll 2
    for (int u = u0; u < u1; ++u) {
        float4 a0 = *(const float4*)(aP);
        float4 a1 = *(const float4*)(aP + 4);
        short8 bf0 = *(const short8*)(bP);
        short8 bf1 = *(const short8*)(bP + 512);    // +1024 B -> immediate offset
        short8 bf2 = *(const short8*)(bP + 1024);
        short8 bf3 = *(const short8*)(bP + 1536);
        short8 af;
        unsigned* afu = (unsigned*)&af;
        afu[0] = pk2(a0.y, a0.x);
        afu[1] = pk2(a0.w, a0.z);
        afu[2] = pk2(a1.y, a1.x);
        afu[3] = pk2(a1.w, a1.z);
        acc[0] = __builtin_amdgcn_mfma_f32_16x16x32_bf16(af, bf0, acc[0], 0, 0, 0);
        acc[1] = __builtin_amdgcn_mfma_f32_16x16x32_bf16(af, bf1, acc[1], 0, 0, 0);
        acc[2] = __builtin_amdgcn_mfma_f32_16x16x32_bf16(af, bf2, acc[2], 0, 0, 0);
        acc[3] = __builtin_amdgcn_mfma_f32_16x16x32_bf16(af, bf3, acc[3], 0, 0, 0);
        accS   = __builtin_amdgcn_mfma_f32_16x16x32_bf16(af, ones, accS, 0, 0, 0);
        aP += 32;
        bP += 2048;
    }

    if (kb == KSPLIT - 1) {
        // K-tail u=937: A has 16 real k (q<2); B chunk is pre-zero-padded by kT
        short8 af;
        #pragma unroll
        for (int i = 0; i < 8; ++i) af[i] = 0;
        if (q < 2) {
            float4 a0 = *(const float4*)(aP);
            float4 a1 = *(const float4*)(aP + 4);
            unsigned* afu = (unsigned*)&af;
            afu[0] = pk2(a0.y, a0.x);
            afu[1] = pk2(a0.w, a0.z);
            afu[2] = pk2(a1.y, a1.x);
            afu[3] = pk2(a1.w, a1.z);
        }
        short8 bf0 = *(const short8*)(bP);
        short8 bf1 = *(const short8*)(bP + 512);
        short8 bf2 = *(const short8*)(bP + 1024);
        short8 bf3 = *(const short8*)(bP + 1536);
        acc[0] = __builtin_amdgcn_mfma_f32_16x16x32_bf16(af, bf0, acc[0], 0, 0, 0);
        acc[1] = __builtin_amdgcn_mfma_f32_16x16x32_bf16(af, bf1, acc[1], 0, 0, 0);
        acc[2] = __builtin_amdgcn_mfma_f32_16x16x32_bf16(af, bf2, acc[2], 0, 0, 0);
        acc[3] = __builtin_amdgcn_mfma_f32_16x16x32_bf16(af, bf3, acc[3], 0, 0, 0);
        accS   = __builtin_amdgcn_mfma_f32_16x16x32_bf16(af, ones, accS, 0, 0, 0);
    }

    // epilogue: C/D layout is col = lane&15, row = (lane>>4)*4 + reg
    float* Cp = Cpart + (size_t)kb * (2048 * 64);
    #pragma unroll
    for (int r = 0; r < 4; ++r) {
        int row = wr + q * 4 + r;
        #pragma unroll
        for (int n = 0; n < 4; ++n)
            Cp[(size_t)row * 64 + n * 16 + r15] = acc[n][r];
        if (r15 == 0) Rpart[kb * 2048 + row] = accS[r];
    }
}

// ---------------- Kernel G2: fused embed-finish + gate GEMM (MFMA) + h0 -------------------------
__global__ __launch_bounds__(256) void kG2(const float* __restrict__ Cpart, const float* __restrict__ Rpart,
                                           const float* __restrict__ Wir, const float* __restrict__ Wiz,
                                           const float* __restrict__ Win,
                                           const float* __restrict__ bir, const float* __restrict__ biz,
                                           const float* __restrict__ bin,
                                           float* __restrict__ Xr, float* __restrict__ Xz,
                                           float* __restrict__ Xn, float* __restrict__ H0) {
    __shared__ __align__(16) u16 eL[64 * 72];
    __shared__ float rsinv[64];
    int tid = threadIdx.x;
    int m0 = blockIdx.x * 64;

    if (tid < 64) {
        float rs = 0.f;
        #pragma unroll
        for (int kb = 0; kb < KSPLIT; ++kb)
            rs += Rpart[kb * 2048 + m0 + tid];
        rsinv[tid] = 1.f / rs;
    }
    float4 a4[4];
    #pragma unroll
    for (int r = 0; r < 4; ++r) { a4[r].x = 0.f; a4[r].y = 0.f; a4[r].z = 0.f; a4[r].w = 0.f; }
    const float* cp = Cpart + (size_t)m0 * 64 + tid * 4;
    #pragma unroll 4
    for (int kb = 0; kb < KSPLIT; ++kb) {
        #pragma unroll
        for (int r = 0; r < 4; ++r) {
            float4 v = *(const float4*)(cp + (size_t)kb * (2048 * 64) + r * 1024);
            a4[r].x += v.x; a4[r].y += v.y; a4[r].z += v.z; a4[r].w += v.w;
        }
    }
    __syncthreads();
    #pragma unroll
    for (int r = 0; r < 4; ++r) {
        int m = r * 16 + (tid >> 4);
        float ri = rsinv[m];
        float e0 = a4[r].x * ri, e1 = a4[r].y * ri, e2 = a4[r].z * ri, e3 = a4[r].w * ri;
        e0 = e0 > 0.f ? e0 : 0.f;  e1 = e1 > 0.f ? e1 : 0.f;
        e2 = e2 > 0.f ? e2 : 0.f;  e3 = e3 > 0.f ? e3 : 0.f;
        ushort4 s;
        s.x = f2b(e0); s.y = f2b(e1); s.z = f2b(e2); s.w = f2b(e3);
        *(ushort4*)&eL[m * 72 + (tid & 15) * 4] = s;
    }
    __syncthreads();

    int w = tid >> 6, l = tid & 63;
    int r15 = l & 15, q = l >> 4;
    short8 a0 = *(const short8*)&eL[(w * 16 + r15) * 72 + q * 8];
    short8 a1 = *(const short8*)&eL[(w * 16 + r15) * 72 + 32 + q * 8];

    floatx4 acc[3][4] = {};
    #pragma unroll
    for (int g = 0; g < 3; ++g) {
        const float* W = (g == 0) ? Wir : (g == 1) ? Wiz : Win;
        #pragma unroll
        for (int nb = 0; nb < 4; ++nb) {
            const float* wrow = W + (nb * 16 + r15) * 64 + q * 8;
            float4 w0 = *(const float4*)(wrow);
            float4 w1 = *(const float4*)(wrow + 4);
            float4 w2 = *(const float4*)(wrow + 32);
            float4 w3 = *(const float4*)(wrow + 36);
            short8 b0, b1;
            unsigned* b0u = (unsigned*)&b0; unsigned* b1u = (unsigned*)&b1;
            b0u[0] = pk2(w0.y, w0.x); b0u[1] = pk2(w0.w, w0.z);
            b0u[2] = pk2(w1.y, w1.x); b0u[3] = pk2(w1.w, w1.z);
            b1u[0] = pk2(w2.y, w2.x); b1u[1] = pk2(w2.w, w2.z);
            b1u[2] = pk2(w3.y, w3.x); b1u[3] = pk2(w3.w, w3.z);
            acc[g][nb] = __builtin_amdgcn_mfma_f32_16x16x32_bf16(a0, b0, acc[g][nb], 0, 0, 0);
            acc[g][nb] = __builtin_amdgcn_mfma_f32_16x16x32_bf16(a1, b1, acc[g][nb], 0, 0, 0);
        }
    }

    #pragma unroll
    for (int g = 0; g < 3; ++g) {
        float* Xo = (g == 0) ? Xr : (g == 1) ? Xz : Xn;
        const float* bo = (g == 0) ? bir : (g == 1) ? biz : bin;
        #pragma unroll
        for (int nb = 0; nb < 4; ++nb) {
            int j = nb * 16 + r15;
            float bias = bo[j];
            #pragma unroll
            for (int r = 0; r < 4; ++r) {
                int m = m0 + w * 16 + q * 4 + r;
                Xo[(size_t)m * 64 + j] = acc[g][nb][r] + bias;
            }
        }
    }
    if (w == 0 && q == 0) {
        #pragma unroll
        for (int nb = 0; nb < 4; ++nb) {
            int j = nb * 16 + r15;
            float z1 = sigmoid_f(acc[1][nb][0] + biz[j]);
            float n1 = tanh_f(acc[2][nb][0] + bin[j]);
            H0[blockIdx.x * 64 + j] = (1.f - z1) * n1;
        }
    }
}

// ---------------- Kernel S2: barrier-free single-wave GRU scan + output proj --------------------
// one wave per batch; lane i owns h_i; h_j broadcast via v_readlane (wave-uniform j)
__global__ __launch_bounds__(64) void kS2(const float* __restrict__ Xr, const float* __restrict__ Xz,
                                          const float* __restrict__ Xn, const float* __restrict__ H0,
                                          const float* __restrict__ Whr, const float* __restrict__ Whz,
                                          const float* __restrict__ bhr, const float* __restrict__ bhz,
                                          const float* __restrict__ Wout, const float* __restrict__ bout,
                                          float* __restrict__ out) {
    int b = blockIdx.x;
    int i = threadIdx.x;
    __shared__ float Xs[3][64][64];
    __shared__ float hsh[64];

    const float* s0 = Xr + (size_t)b * 4096;
    const float* s1 = Xz + (size_t)b * 4096;
    const float* s2 = Xn + (size_t)b * 4096;
    #pragma unroll
    for (int c = 0; c < 16; ++c) {
        int off = (c * 64 + i) * 4;
        *(float4*)&Xs[0][0][off] = *(const float4*)(s0 + off);
        *(float4*)&Xs[1][0][off] = *(const float4*)(s1 + off);
        *(float4*)&Xs[2][0][off] = *(const float4*)(s2 + off);
    }
    float wrg[64], wzg[64];
    #pragma unroll
    for (int c = 0; c < 16; ++c) {
        float4 v1 = *(const float4*)(Whr + i * 64 + c * 4);
        float4 v2 = *(const float4*)(Whz + i * 64 + c * 4);
        wrg[c * 4 + 0] = v1.x; wrg[c * 4 + 1] = v1.y; wrg[c * 4 + 2] = v1.z; wrg[c * 4 + 3] = v1.w;
        wzg[c * 4 + 0] = v2.x; wzg[c * 4 + 1] = v2.y; wzg[c * 4 + 2] = v2.z; wzg[c * 4 + 3] = v2.w;
    }
    float h = H0[b * 64 + i];
    float bri = bhr[i], bzi = bhz[i];

    for (int t = 1; t < 64; ++t) {
        float xr = Xs[0][t][i], xz = Xs[1][t][i], xn = Xs[2][t][i];
        float p0 = 0.f, p1 = 0.f, p2 = 0.f, p3 = 0.f;
        float z0 = 0.f, z1 = 0.f, z2 = 0.f, z3 = 0.f;
        unsigned hu = __float_as_uint(h);
        #pragma unroll
        for (int j = 0; j < 64; j += 4) {
            float h0 = __uint_as_float(__builtin_amdgcn_readlane(hu, j + 0));
            float h1 = __uint_as_float(__builtin_amdgcn_readlane(hu, j + 1));
            float h2 = __uint_as_float(__builtin_amdgcn_readlane(hu, j + 2));
            float h3 = __uint_as_float(__builtin_amdgcn_readlane(hu, j + 3));
            p0 += h0 * wrg[j + 0]; p1 += h1 * wrg[j + 1];
            p2 += h2 * wrg[j + 2]; p3 += h3 * wrg[j + 3];
            z0 += h0 * wzg[j + 0]; z1 += h1 * wzg[j + 1];
            z2 += h2 * wzg[j + 2]; z3 += h3 * wzg[j + 3];
        }
        float hr = bri + ((p0 + p1) + (p2 + p3));
        float hz = bzi + ((z0 + z1) + (z2 + z3));
        float r = sigmoid_f(xr + hr);
        float z = sigmoid_f(xz + hz);
        float n = tanh_f(xn + r * hr);     // ref uses r*hr: W_hn/b_hn are dead
        h = (1.f - z) * n + z * h;
    }

    hsh[i] = h;
    __syncthreads();
    if (i < OO) {
        float a = bout[i];
        #pragma unroll 8
        for (int j = 0; j < 64; ++j)
            a += hsh[j] * Wout[i * 64 + j];
        out[b * OO + i] = a;
    }
}

extern "C" void kernel_launch(void* const* d_in, const int* in_sizes, int n_in,
                              void* d_out, int out_size, void* d_ws, size_t ws_size,
                              hipStream_t stream) {
    const float* x    = (const float*)d_in[0];
    const float* VE   = (const float*)d_in[1];
    const float* Wir  = (const float*)d_in[2];
    const float* Wiz  = (const float*)d_in[3];
    const float* Win  = (const float*)d_in[4];
    const float* Whr  = (const float*)d_in[5];
    const float* Whz  = (const float*)d_in[6];
    // d_in[7] = W_hn (dead in the reference recurrence)
    const float* bir  = (const float*)d_in[8];
    const float* biz  = (const float*)d_in[9];
    const float* bin  = (const float*)d_in[10];
    const float* bhr  = (const float*)d_in[11];
    const float* bhz  = (const float*)d_in[12];
    // d_in[13] = b_hn (dead)
    const float* Wout = (const float*)d_in[14];
    const float* bout = (const float*)d_in[15];

    char* ws = (char*)d_ws;
    u16*   VTf   = (u16*)(ws);                              //  938*4096 = 3,842,048 B
    float* Cpart = (float*)(ws + 4000000);                  // 16,777,216 B
    float* Rpart = (float*)(ws + 20777216);                 //    262,144 B
    float* Xr    = (float*)(ws + 21039360);                 //    524,288 B
    float* Xz    = (float*)(ws + 21563648);                 //    524,288 B
    float* Xn    = (float*)(ws + 22087936);                 //    524,288 B
    float* H0    = (float*)(ws + 22612224);                 //      8,192 B

    kT<<<469, 256, 0, stream>>>(VE, VTf);                   // 469*64 = 30016 v's (pad zeroed)
    kE<<<dim3(2048 / 64, KSPLIT), 256, 0, stream>>>(x, VTf, Cpart, Rpart);
    kG2<<<32, 256, 0, stream>>>(Cpart, Rpart, Wir, Wiz, Win, bir, biz, bin, Xr, Xz, Xn, H0);
    kS2<<<BB, 64, 0, stream>>>(Xr, Xz, Xn, H0, Whr, Whz, bhr, bhz, Wout, bout, (float*)d_out);
}

// Round 5
// 423.327 us; speedup vs baseline: 1.0635x; 1.0282x over previous
//
#include <hip/hip_runtime.h>
#include <hip/hip_bf16.h>

typedef unsigned short u16;
typedef short short8 __attribute__((ext_vector_type(8)));
typedef float floatx4 __attribute__((ext_vector_type(4)));

#define BB 32
#define TT 64
#define VV 30000
#define EE 64
#define HH 64
#define OO 7
#define KSPLIT 32
#define NU32 937        /* full 32-wide k units: 937*32 = 29984, tail 16 */

__device__ __forceinline__ u16 f2b(float f) {   // fp32 -> bf16, round-to-nearest-even
    unsigned u = __float_as_uint(f);
    u += 0x7FFFu + ((u >> 16) & 1u);
    return (u16)(u >> 16);
}

// pack hi16(fe), hi16(fo) -> one VGPR via v_perm_b32 (bf16 truncation)
__device__ __forceinline__ unsigned pk2(float fo, float fe) {
    return __builtin_amdgcn_perm(__float_as_uint(fo), __float_as_uint(fe), 0x07060302u);
}

__device__ __forceinline__ float sigmoid_f(float x) {
    return 1.f / (1.f + __expf(-x));
}

__device__ __forceinline__ float tanh_f(float x) {
    float a = fabsf(x);
    float e = __expf(-2.f * a);
    float t = (1.f - e) / (1.f + e);
    return x < 0.f ? -t : t;
}

// ---------------- Kernel T: VE (V x E fp32) -> fragment-major bf16 VTf ----
// VTf chunk u (4 KB): [nb 0..3][r15 0..15][k 0..31] = B[k = u*32+k][n = nb*16+r15]
// chunks u = 0..937; u=937 has k>=16 zero-padded (and v>=30000 zero).
__global__ __launch_bounds__(256) void kT(const float* __restrict__ VE, u16* __restrict__ VTf) {
    __shared__ u16 tile[64][72];
    int v0 = blockIdx.x * 64;
    int t = threadIdx.x;
    #pragma unroll
    for (int it = 0; it < 4; ++it) {
        int c = it * 256 + t;                // 1024 float4 chunks: 64 rows x 16 chunks
        int row = c >> 4, col4 = (c & 15) * 4;
        ushort4 s; s.x = 0; s.y = 0; s.z = 0; s.w = 0;
        if (v0 + row < VV) {
            float4 d = *(const float4*)(VE + (size_t)(v0 + row) * EE + col4);
            s.x = f2b(d.x); s.y = f2b(d.y); s.z = f2b(d.z); s.w = f2b(d.w);
        }
        *(ushort4*)&tile[row][col4] = s;
    }
    __syncthreads();
    int e = t & 63;
    int nb = e >> 4, r = e & 15;
    #pragma unroll
    for (int half = 0; half < 2; ++half) {
        int q8 = (t >> 6) + half * 4;        // 0..7 -> v-local = q8*8 .. +7
        int u = (v0 >> 5) + (q8 >> 2);
        int kin = (q8 & 3) * 8;
        u16 tmp[8];
        #pragma unroll
        for (int jj = 0; jj < 8; ++jj) tmp[jj] = tile[q8 * 8 + jj][e];
        *(uint4*)&VTf[(size_t)u * 2048 + nb * 512 + r * 32 + kin] = *(uint4*)tmp;
    }
}

// ---------------- Kernel E: embed GEMM (split-K, no LDS, no barriers) + fused row-sum ----------
__global__ __launch_bounds__(256) void kE(const float* __restrict__ x, const u16* __restrict__ vtf,
                                          float* __restrict__ Cpart, float* __restrict__ Rpart) {
    int tid = threadIdx.x;
    int w = tid >> 6, l = tid & 63;
    int r15 = l & 15, q = l >> 4;
    int mb = blockIdx.x, kb = blockIdx.y;
    int m0 = mb * 64;
    int wr = m0 + w * 16;                    // this wave's 16 m-rows
    int u0 = (kb * NU32) / KSPLIT, u1 = ((kb + 1) * NU32) / KSPLIT;

    const float* aP = x + (size_t)(wr + r15) * VV + u0 * 32 + q * 8;
    const u16*   bP = vtf + (size_t)u0 * 2048 + r15 * 32 + q * 8;

    floatx4 acc[4] = {};
    floatx4 accS = {};
    short8 ones;
    #pragma unroll
    for (int i = 0; i < 8; ++i) ones[i] = (short)0x3F80;   // bf16 1.0

    #pragma unroll 4
    for (int u = u0; u < u1; ++u) {
        float4 a0 = *(const float4*)(aP);
        float4 a1 = *(const float4*)(aP + 4);
        short8 bf0 = *(const short8*)(bP);
        short8 bf1 = *(const short8*)(bP + 512);    // +1024 B -> immediate offset
        short8 bf2 = *(const short8*)(bP + 1024);
        short8 bf3 = *(const short8*)(bP + 1536);
        short8 af;
        unsigned* afu = (unsigned*)&af;
        afu[0] = pk2(a0.y, a0.x);
        afu[1] = pk2(a0.w, a0.z);
        afu[2] = pk2(a1.y, a1.x);
        afu[3] = pk2(a1.w, a1.z);
        acc[0] = __builtin_amdgcn_mfma_f32_16x16x32_bf16(af, bf0, acc[0], 0, 0, 0);
        acc[1] = __builtin_amdgcn_mfma_f32_16x16x32_bf16(af, bf1, acc[1], 0, 0, 0);
        acc[2] = __builtin_amdgcn_mfma_f32_16x16x32_bf16(af, bf2, acc[2], 0, 0, 0);
        acc[3] = __builtin_amdgcn_mfma_f32_16x16x32_bf16(af, bf3, acc[3], 0, 0, 0);
        accS   = __builtin_amdgcn_mfma_f32_16x16x32_bf16(af, ones, accS, 0, 0, 0);
        aP += 32;
        bP += 2048;
    }

    if (kb == KSPLIT - 1) {
        // K-tail u=937: A has 16 real k (q<2); B chunk is pre-zero-padded by kT
        short8 af;
        #pragma unroll
        for (int i = 0; i < 8; ++i) af[i] = 0;
        if (q < 2) {
            float4 a0 = *(const float4*)(aP);
            float4 a1 = *(const float4*)(aP + 4);
            unsigned* afu = (unsigned*)&af;
            afu[0] = pk2(a0.y, a0.x);
            afu[1] = pk2(a0.w, a0.z);
            afu[2] = pk2(a1.y, a1.x);
            afu[3] = pk2(a1.w, a1.z);
        }
        short8 bf0 = *(const short8*)(bP);
        short8 bf1 = *(const short8*)(bP + 512);
        short8 bf2 = *(const short8*)(bP + 1024);
        short8 bf3 = *(const short8*)(bP + 1536);
        acc[0] = __builtin_amdgcn_mfma_f32_16x16x32_bf16(af, bf0, acc[0], 0, 0, 0);
        acc[1] = __builtin_amdgcn_mfma_f32_16x16x32_bf16(af, bf1, acc[1], 0, 0, 0);
        acc[2] = __builtin_amdgcn_mfma_f32_16x16x32_bf16(af, bf2, acc[2], 0, 0, 0);
        acc[3] = __builtin_amdgcn_mfma_f32_16x16x32_bf16(af, bf3, acc[3], 0, 0, 0);
        accS   = __builtin_amdgcn_mfma_f32_16x16x32_bf16(af, ones, accS, 0, 0, 0);
    }

    // epilogue: C/D layout is col = lane&15, row = (lane>>4)*4 + reg
    float* Cp = Cpart + (size_t)kb * (2048 * 64);
    #pragma unroll
    for (int r = 0; r < 4; ++r) {
        int row = wr + q * 4 + r;
        #pragma unroll
        for (int n = 0; n < 4; ++n)
            Cp[(size_t)row * 64 + n * 16 + r15] = acc[n][r];
        if (r15 == 0) Rpart[kb * 2048 + row] = accS[r];
    }
}

// ---------------- Kernel GS: fused embed-finish + gate GEMM + GRU scan + output proj ------------
// one block per batch b; block's 64 m-rows (m = b*64 + t) are exactly batch b's 64 timesteps.
// Phase 1 (256 thr): Cpart reduce -> e -> 3 gate GEMMs -> Xs[3][t][j] in LDS + h0.
// Phase 2 (wave 0): barrier-free readlane scan + output projection.
__global__ __launch_bounds__(256) void kGS(const float* __restrict__ Cpart, const float* __restrict__ Rpart,
                                           const float* __restrict__ Wir, const float* __restrict__ Wiz,
                                           const float* __restrict__ Win,
                                           const float* __restrict__ bir, const float* __restrict__ biz,
                                           const float* __restrict__ bin,
                                           const float* __restrict__ Whr, const float* __restrict__ Whz,
                                           const float* __restrict__ bhr, const float* __restrict__ bhz,
                                           const float* __restrict__ Wout, const float* __restrict__ bout,
                                           float* __restrict__ out) {
    __shared__ __align__(16) u16 eL[64 * 72];
    __shared__ float rsinv[64];
    __shared__ float Xs[3][64][64];
    __shared__ float hsh[64];
    int tid = threadIdx.x;
    int b = blockIdx.x;
    int m0 = b * 64;

    // --- phase 1a: row-sum reduction ---
    if (tid < 64) {
        float rs = 0.f;
        #pragma unroll
        for (int kb = 0; kb < KSPLIT; ++kb)
            rs += Rpart[kb * 2048 + m0 + tid];
        rsinv[tid] = 1.f / rs;
    }
    // --- phase 1b: Cpart reduction, coalesced (16 KB contiguous per kb) ---
    float4 a4[4];
    #pragma unroll
    for (int r = 0; r < 4; ++r) { a4[r].x = 0.f; a4[r].y = 0.f; a4[r].z = 0.f; a4[r].w = 0.f; }
    const float* cp = Cpart + (size_t)m0 * 64 + tid * 4;
    #pragma unroll 4
    for (int kb = 0; kb < KSPLIT; ++kb) {
        #pragma unroll
        for (int r = 0; r < 4; ++r) {
            float4 v = *(const float4*)(cp + (size_t)kb * (2048 * 64) + r * 1024);
            a4[r].x += v.x; a4[r].y += v.y; a4[r].z += v.z; a4[r].w += v.w;
        }
    }
    __syncthreads();
    #pragma unroll
    for (int r = 0; r < 4; ++r) {
        int m = r * 16 + (tid >> 4);
        float ri = rsinv[m];
        float e0 = a4[r].x * ri, e1 = a4[r].y * ri, e2 = a4[r].z * ri, e3 = a4[r].w * ri;
        e0 = e0 > 0.f ? e0 : 0.f;  e1 = e1 > 0.f ? e1 : 0.f;
        e2 = e2 > 0.f ? e2 : 0.f;  e3 = e3 > 0.f ? e3 : 0.f;
        ushort4 s;
        s.x = f2b(e0); s.y = f2b(e1); s.z = f2b(e2); s.w = f2b(e3);
        *(ushort4*)&eL[m * 72 + (tid & 15) * 4] = s;
    }
    __syncthreads();

    // --- phase 1c: three gate GEMMs, 16x16x32 MFMA, K=64 ---
    int w = tid >> 6, l = tid & 63;
    int r15 = l & 15, q = l >> 4;
    short8 fa0 = *(const short8*)&eL[(w * 16 + r15) * 72 + q * 8];
    short8 fa1 = *(const short8*)&eL[(w * 16 + r15) * 72 + 32 + q * 8];

    floatx4 acc[3][4] = {};
    #pragma unroll
    for (int g = 0; g < 3; ++g) {
        const float* W = (g == 0) ? Wir : (g == 1) ? Wiz : Win;
        #pragma unroll
        for (int nb = 0; nb < 4; ++nb) {
            const float* wrow = W + (nb * 16 + r15) * 64 + q * 8;
            float4 w0 = *(const float4*)(wrow);
            float4 w1 = *(const float4*)(wrow + 4);
            float4 w2 = *(const float4*)(wrow + 32);
            float4 w3 = *(const float4*)(wrow + 36);
            short8 b0, b1;
            unsigned* b0u = (unsigned*)&b0; unsigned* b1u = (unsigned*)&b1;
            b0u[0] = pk2(w0.y, w0.x); b0u[1] = pk2(w0.w, w0.z);
            b0u[2] = pk2(w1.y, w1.x); b0u[3] = pk2(w1.w, w1.z);
            b1u[0] = pk2(w2.y, w2.x); b1u[1] = pk2(w2.w, w2.z);
            b1u[2] = pk2(w3.y, w3.x); b1u[3] = pk2(w3.w, w3.z);
            acc[g][nb] = __builtin_amdgcn_mfma_f32_16x16x32_bf16(fa0, b0, acc[g][nb], 0, 0, 0);
            acc[g][nb] = __builtin_amdgcn_mfma_f32_16x16x32_bf16(fa1, b1, acc[g][nb], 0, 0, 0);
        }
    }

    // --- phase 1d: bias + store gates into LDS; C/D layout col=lane&15, row=q*4+reg ---
    #pragma unroll
    for (int g = 0; g < 3; ++g) {
        const float* bo = (g == 0) ? bir : (g == 1) ? biz : bin;
        #pragma unroll
        for (int nb = 0; nb < 4; ++nb) {
            int j = nb * 16 + r15;
            float bias = bo[j];
            #pragma unroll
            for (int r = 0; r < 4; ++r) {
                int t = w * 16 + q * 4 + r;          // local row == timestep
                Xs[g][t][j] = acc[g][nb][r] + bias;
            }
        }
    }
    if (w == 0 && q == 0) {                          // t == 0 row: initial hidden state
        #pragma unroll
        for (int nb = 0; nb < 4; ++nb) {
            int j = nb * 16 + r15;
            float z1 = sigmoid_f(acc[1][nb][0] + biz[j]);
            float n1 = tanh_f(acc[2][nb][0] + bin[j]);
            hsh[j] = (1.f - z1) * n1;
        }
    }
    __syncthreads();

    // --- phase 2: wave-0-only barrier-free scan; lane i owns h_i ---
    if (tid >= 64) return;
    int i = tid;
    float wrg[64], wzg[64];
    #pragma unroll
    for (int c = 0; c < 16; ++c) {
        float4 v1 = *(const float4*)(Whr + i * 64 + c * 4);
        float4 v2 = *(const float4*)(Whz + i * 64 + c * 4);
        wrg[c * 4 + 0] = v1.x; wrg[c * 4 + 1] = v1.y; wrg[c * 4 + 2] = v1.z; wrg[c * 4 + 3] = v1.w;
        wzg[c * 4 + 0] = v2.x; wzg[c * 4 + 1] = v2.y; wzg[c * 4 + 2] = v2.z; wzg[c * 4 + 3] = v2.w;
    }
    float h = hsh[i];
    float bri = bhr[i], bzi = bhz[i];

    for (int t = 1; t < 64; ++t) {
        float xr = Xs[0][t][i], xz = Xs[1][t][i], xn = Xs[2][t][i];
        float p0 = 0.f, p1 = 0.f, p2 = 0.f, p3 = 0.f;
        float z0 = 0.f, z1 = 0.f, z2 = 0.f, z3 = 0.f;
        unsigned hu = __float_as_uint(h);
        #pragma unroll
        for (int j = 0; j < 64; j += 4) {
            float h0 = __uint_as_float(__builtin_amdgcn_readlane(hu, j + 0));
            float h1 = __uint_as_float(__builtin_amdgcn_readlane(hu, j + 1));
            float h2 = __uint_as_float(__builtin_amdgcn_readlane(hu, j + 2));
            float h3 = __uint_as_float(__builtin_amdgcn_readlane(hu, j + 3));
            p0 += h0 * wrg[j + 0]; p1 += h1 * wrg[j + 1];
            p2 += h2 * wrg[j + 2]; p3 += h3 * wrg[j + 3];
            z0 += h0 * wzg[j + 0]; z1 += h1 * wzg[j + 1];
            z2 += h2 * wzg[j + 2]; z3 += h3 * wzg[j + 3];
        }
        float hr = bri + ((p0 + p1) + (p2 + p3));
        float hz = bzi + ((z0 + z1) + (z2 + z3));
        float r = sigmoid_f(xr + hr);
        float z = sigmoid_f(xz + hz);
        float n = tanh_f(xn + r * hr);     // ref uses r*hr: W_hn/b_hn are dead
        h = (1.f - z) * n + z * h;
    }

    hsh[i] = h;                            // wave-internal LDS ops are in program order
    if (i < OO) {
        float a = bout[i];
        #pragma unroll 8
        for (int j = 0; j < 64; ++j)
            a += hsh[j] * Wout[i * 64 + j];
        out[b * OO + i] = a;
    }
}

extern "C" void kernel_launch(void* const* d_in, const int* in_sizes, int n_in,
                              void* d_out, int out_size, void* d_ws, size_t ws_size,
                              hipStream_t stream) {
    const float* x    = (const float*)d_in[0];
    const float* VE   = (const float*)d_in[1];
    const float* Wir  = (const float*)d_in[2];
    const float* Wiz  = (const float*)d_in[3];
    const float* Win  = (const float*)d_in[4];
    const float* Whr  = (const float*)d_in[5];
    const float* Whz  = (const float*)d_in[6];
    // d_in[7] = W_hn (dead in the reference recurrence)
    const float* bir  = (const float*)d_in[8];
    const float* biz  = (const float*)d_in[9];
    const float* bin  = (const float*)d_in[10];
    const float* bhr  = (const float*)d_in[11];
    const float* bhz  = (const float*)d_in[12];
    // d_in[13] = b_hn (dead)
    const float* Wout = (const float*)d_in[14];
    const float* bout = (const float*)d_in[15];

    char* ws = (char*)d_ws;
    u16*   VTf   = (u16*)(ws);                              //  938*4096 = 3,842,048 B
    float* Cpart = (float*)(ws + 4000000);                  // 16,777,216 B
    float* Rpart = (float*)(ws + 20777216);                 //    262,144 B

    kT<<<469, 256, 0, stream>>>(VE, VTf);                   // 469*64 = 30016 v's (pad zeroed)
    kE<<<dim3(2048 / 64, KSPLIT), 256, 0, stream>>>(x, VTf, Cpart, Rpart);
    kGS<<<BB, 256, 0, stream>>>(Cpart, Rpart, Wir, Wiz, Win, bir, biz, bin,
                                Whr, Whz, bhr, bhz, Wout, bout, (float*)d_out);
}